// Round 2
// baseline (1497.392 us; speedup 1.0000x reference)
//
#include <hip/hip_runtime.h>
#include <hip/hip_bf16.h>
#include <math.h>

// ---------------------------------------------------------------------------
// BigHeteroGNN — ROUND 7: edge_agg ILP.
// R6 profile: edge_agg 6x95us dominates; MfmaUtil 0 / HBM 18% / VALU 41% =
// serial-chain latency (per edge: gather -> 4 dependent ds_swizzle -> 2 exp,
// carried through online-softmax state; avg degree ~4, no compiler unroll).
// Now: 4 independent softmax states per wave (4 edges/iter, interleaved
// chains), VALU-only state merge at node end; exp->exp2 with log2e folded
// into K prep (saves muls in the carried chain). proj_fused 1024 threads
// (4 waves/SIMD vs 2) for better A-prefetch latency hiding.
// ---------------------------------------------------------------------------

typedef __bf16 bf16;
typedef __bf16 bf16x8 __attribute__((ext_vector_type(8)));
typedef float  f32x4  __attribute__((ext_vector_type(4)));

#define NE 200000
#define N0T 100000
#define N1T 150000
#define N2T 50000
#define BPITCH 136          // 272B stride -> 2-way LDS bank alias (free, m136)
#define QGELEMS 38400000    // 300000 * 128
// fold: 1/sqrt(32) * log2(e)  (alpha kept in log2 domain; softmax invariant)
#define KSCALE (0.17677669529663687f * 1.4426950408889634f)

__device__ inline float bflo(unsigned u) { return __uint_as_float(u << 16); }
__device__ inline float bfhi(unsigned u) { return __uint_as_float(u & 0xFFFF0000u); }
__device__ inline unsigned f2bfbits(float f) {
    unsigned x = __float_as_uint(f);
    return ((x + 0x7FFFu + ((x >> 16) & 1u)) >> 16) & 0xFFFFu;  // RNE
}
__device__ inline float gelu_exact(float x) {
    return 0.5f * x * (1.0f + erff(x * 0.70710678118654752f));
}
__device__ inline float ldx(const void* p, size_t i, int f) {
    return f ? ((const float*)p)[i] : (float)((const bf16*)p)[i];
}

// ---------------------------------------------------------------------------
// Dtype detection (validated R4): 1 = float32, 0 = bf16.
// ---------------------------------------------------------------------------
__device__ inline int plausible(float v) {
    float a = fabsf(v);
    return (v == 0.f) || (a > 1e-8f && a < 1e8f);
}

__global__ void detect_k(const void* p, int* flag) {
    __shared__ int cF, cB;
    int tid = threadIdx.x;
    if (tid == 0) { cF = 0; cB = 0; }
    __syncthreads();
    float vf = ((const float*)p)[tid];
    float b0 = (float)((const bf16*)p)[2 * tid];
    float b1 = (float)((const bf16*)p)[2 * tid + 1];
    if (plausible(vf)) atomicAdd(&cF, 1);
    if (plausible(b0) && plausible(b1)) atomicAdd(&cB, 1);
    __syncthreads();
    if (tid == 0) *flag = (cF > cB) ? 1 : 0;
}

__global__ void conv_f32_k(const void* src, float* dst, int n, const int* flagp) {
    int f = *flagp;
    int i = blockIdx.x * 256 + threadIdx.x;
    if (i >= n) return;
    dst[i] = ldx(src, i, f);
}

// ---------------------------------------------------------------------------
// Weight prep (canonical bf16, TRANSPOSED for B-staging: WT[col][k])
// ---------------------------------------------------------------------------
__global__ void transpose128f(const void* W, bf16* __restrict__ WT, const int* fwp) {
    int fw = *fwp;
    int gid = blockIdx.x * 256 + threadIdx.x;
    if (gid >= 3 * 16384) return;
    int t = gid >> 14, r = (gid >> 7) & 127, c = gid & 127;
    WT[gid] = (bf16)ldx(W, (size_t)(t << 14) + c * 128 + r, fw);
}

// WkvT[e][kind][j][i] = (w @ blockdiag(rel))[i][j]; kind0=k(arel*prel*log2e/sqrt d),1=v(mrel)
__global__ void prep_kv(const void* kw, const void* vw, const void* arel,
                        const void* mrel, const void* prel,
                        bf16* __restrict__ WkvT, const int* fwp) {
    int fw = *fwp;
    int gid = blockIdx.x * 256 + threadIdx.x;
    if (gid >= 4 * 2 * 128 * 128) return;
    int i = gid & 127;
    int j = (gid >> 7) & 127;
    int kind = (gid >> 14) & 1;
    int e = gid >> 15;
    const int stab[4] = {1, 2, 0, 0};
    int st = stab[e];
    int h = j >> 5, jj = j & 31;
    size_t wbase = (size_t)st * 16384;
    size_t rbase = (size_t)(e * 4 + h) * 1024;
    const void* w   = kind ? vw : kw;
    const void* rel = kind ? mrel : arel;
    float acc = 0.f;
    for (int d = 0; d < 32; ++d)
        acc += ldx(w, wbase + (size_t)i * 128 + h * 32 + d, fw) *
               ldx(rel, rbase + (size_t)d * 32 + jj, fw);
    if (!kind)
        acc *= ldx(prel, e * 4 + h, fw) * KSCALE;
    WkvT[((size_t)(e * 2 + kind) * 128 + j) * 128 + i] = (bf16)acc;
}

__global__ void prep_kvbias(const void* kb, const void* vb, const void* arel,
                            const void* mrel, const void* prel,
                            float* __restrict__ Bf, const int* fwp) {
    int fw = *fwp;
    int gid = blockIdx.x * 256 + threadIdx.x;
    if (gid >= 4 * 2 * 128) return;
    int j = gid & 127;
    int kind = (gid >> 7) & 1;
    int e = gid >> 8;
    const int stab[4] = {1, 2, 0, 0};
    int st = stab[e];
    int h = j >> 5, jj = j & 31;
    const void* b   = kind ? vb : kb;
    const void* rel = kind ? mrel : arel;
    float acc = 0.f;
    for (int d = 0; d < 32; ++d)
        acc += ldx(b, (size_t)st * 128 + h * 32 + d, fw) *
               ldx(rel, (size_t)(e * 4 + h) * 1024 + (size_t)d * 32 + jj, fw);
    if (!kind)
        acc *= ldx(prel, e * 4 + h, fw) * KSCALE;
    Bf[gid] = acc;
}

// ---------------------------------------------------------------------------
// CSR build (per dst type). Adjacency stores KEVE-buffer row ids (lb[e]+src).
// ---------------------------------------------------------------------------
__global__ void zero_i32(int* p, int n) {
    int i = blockIdx.x * 256 + threadIdx.x;
    if (i < n) p[i] = 0;
}

__global__ void hist_k(const int* __restrict__ e0, const int* __restrict__ e1,
                       const int* __restrict__ e2, const int* __restrict__ e3,
                       int* c0, int* c1, int* c2) {
    int gid = blockIdx.x * 256 + threadIdx.x;
    if (gid >= 4 * NE) return;
    int e = gid / NE, i = gid - e * NE;
    const int* ep = (e == 0) ? e0 : (e == 1) ? e1 : (e == 2) ? e2 : e3;
    int dst = ep[NE + i];
    int* c = (e < 2) ? c0 : (e == 2) ? c1 : c2;
    atomicAdd(&c[dst], 1);
}

__global__ __launch_bounds__(256) void scan1(const int* __restrict__ cnt, int n,
                                             int* __restrict__ excl, int* __restrict__ bsums) {
    __shared__ int s[256];
    int tid = threadIdx.x;
    int base = blockIdx.x * 2048 + tid * 8;
    int v[8]; int tsum = 0;
    for (int j = 0; j < 8; ++j) {
        int idx = base + j;
        int c = (idx < n) ? cnt[idx] : 0;
        v[j] = c; tsum += c;
    }
    s[tid] = tsum; __syncthreads();
    for (int off = 1; off < 256; off <<= 1) {
        int t = 0; if (tid >= off) t = s[tid - off];
        __syncthreads(); s[tid] += t; __syncthreads();
    }
    int run = s[tid] - tsum;
    for (int j = 0; j < 8; ++j) {
        int idx = base + j;
        if (idx < n) excl[idx] = run;
        run += v[j];
    }
    if (tid == 255) bsums[blockIdx.x] = s[255];
}

__global__ void scan2(int* __restrict__ bs, int nb) {
    __shared__ int s[256];
    int tid = threadIdx.x;
    int v = (tid < nb) ? bs[tid] : 0;
    s[tid] = v; __syncthreads();
    for (int off = 1; off < 256; off <<= 1) {
        int t = 0; if (tid >= off) t = s[tid - off];
        __syncthreads(); s[tid] += t; __syncthreads();
    }
    if (tid < nb) bs[tid] = s[tid] - v;
}

__global__ void scan3(int* __restrict__ excl, const int* __restrict__ bs,
                      int* __restrict__ cursor, int n, int total) {
    int idx = blockIdx.x * 256 + threadIdx.x;
    if (idx < n) {
        int v = excl[idx] + bs[idx >> 11];
        excl[idx] = v;
        cursor[idx] = v;
    }
    if (idx == 0) excl[n] = total;
}

__global__ void fill_k(const int* __restrict__ e0, const int* __restrict__ e1,
                       const int* __restrict__ e2, const int* __restrict__ e3,
                       int* c0, int* c1, int* c2,
                       unsigned* a0, unsigned* a1, unsigned* a2,
                       int lb0, int lb1, int lb2, int lb3) {
    int gid = blockIdx.x * 256 + threadIdx.x;
    if (gid >= 4 * NE) return;
    int e = gid / NE, i = gid - e * NE;
    const int* ep = (e == 0) ? e0 : (e == 1) ? e1 : (e == 2) ? e2 : e3;
    int src = ep[i], dst = ep[NE + i];
    int lb = (e == 0) ? lb0 : (e == 1) ? lb1 : (e == 2) ? lb2 : lb3;
    int* c; unsigned* a;
    if (e < 2)      { c = c0; a = a0; }
    else if (e == 2){ c = c1; a = a1; }
    else            { c = c2; a = a2; }
    int pos = atomicAdd(&c[dst], 1);
    a[pos] = (unsigned)(lb + src);
}

// ---------------------------------------------------------------------------
// Persistent fused projection: up to 3 column-groups (Q/K/V) resident in LDS
// (staged ONCE), 1024 threads (16 waves = 4/SIMD), grid-stride over 256-row
// tiles, A software-prefetched one tile ahead, no barriers in the loop.
// ---------------------------------------------------------------------------
__global__ __launch_bounds__(1024) void proj_fused(
    const void* __restrict__ A, long aOff, int nrows,
    const bf16* __restrict__ Wb, const float* __restrict__ Bb,
    bf16* __restrict__ Ob, int ng,
    int w0, int w1, int w2, int b0, int b1, int b2,
    int o0, int o1, int o2, int p0, int p1, int p2,
    const int* fxp)
{
    int fx = *fxp;
    __shared__ bf16 sB[3 * 128 * BPITCH];   // 104448 B
    int tid = threadIdx.x;
    #pragma unroll
    for (int g = 0; g < 3; ++g) {
        if (g >= ng) break;
        const bf16* wt = Wb + ((g == 0) ? w0 : (g == 1) ? w1 : w2);
        for (int it = 0; it < 2; ++it) {
            int idx = it * 1024 + tid;
            int r = idx >> 4, c8 = idx & 15;
            *(bf16x8*)(&sB[(g * 128 + r) * BPITCH + c8 * 8]) =
                *(const bf16x8*)(wt + r * 128 + c8 * 8);
        }
    }
    __syncthreads();

    int lane = tid & 63, wave = tid >> 6;
    int quad = lane >> 4, n16 = lane & 15;

    float bias_r[3][8];
    #pragma unroll
    for (int g = 0; g < 3; ++g) {
        if (g >= ng) break;
        const float* bp = Bb + ((g == 0) ? b0 : (g == 1) ? b1 : b2);
        #pragma unroll
        for (int c = 0; c < 8; ++c) bias_r[g][c] = bp[c * 16 + n16];
    }

    int ntiles = (nrows + 255) >> 8;
    long tile = blockIdx.x;
    if (tile >= ntiles) return;

    float4 rf[8];     // raw f32 prefetch (fx path)
    bf16x8 rb[4];     // raw bf16 prefetch
    bf16x8 afr[4];    // current A fragments

    auto issue = [&](long t) {
        long ar = t * 256 + wave * 16 + n16;
        if (ar >= nrows) ar = nrows - 1;
        size_t base = (size_t)aOff + (size_t)ar * 128 + quad * 8;
        if (fx) {
            const float* ap = (const float*)A + base;
            #pragma unroll
            for (int k = 0; k < 4; ++k) {
                rf[2 * k]     = *(const float4*)(ap + k * 32);
                rf[2 * k + 1] = *(const float4*)(ap + k * 32 + 4);
            }
        } else {
            const bf16* ap = (const bf16*)A + base;
            #pragma unroll
            for (int k = 0; k < 4; ++k) rb[k] = *(const bf16x8*)(ap + k * 32);
        }
    };
    auto cvt = [&]() {
        if (fx) {
            #pragma unroll
            for (int k = 0; k < 4; ++k) {
                float4 u = rf[2 * k], v = rf[2 * k + 1];
                bf16x8 t;
                t[0] = (bf16)u.x; t[1] = (bf16)u.y; t[2] = (bf16)u.z; t[3] = (bf16)u.w;
                t[4] = (bf16)v.x; t[5] = (bf16)v.y; t[6] = (bf16)v.z; t[7] = (bf16)v.w;
                afr[k] = t;
            }
        } else {
            #pragma unroll
            for (int k = 0; k < 4; ++k) afr[k] = rb[k];
        }
    };

    issue(tile);
    cvt();
    for (;;) {
        long next = tile + gridDim.x;
        bool more = (next < ntiles);
        if (more) issue(next);          // prefetch: hides HBM latency under MFMAs
        long rbase = tile * 256 + wave * 16;
        #pragma unroll
        for (int g = 0; g < 3; ++g) {
            if (g >= ng) break;
            bf16* op = Ob + ((g == 0) ? o0 : (g == 1) ? o1 : o2);
            int pg = (g == 0) ? p0 : (g == 1) ? p1 : p2;
            #pragma unroll
            for (int c = 0; c < 8; ++c) {
                f32x4 acc = {0.f, 0.f, 0.f, 0.f};
                const bf16* bp = &sB[(g * 128 + c * 16 + n16) * BPITCH + quad * 8];
                #pragma unroll
                for (int k = 0; k < 4; ++k)
                    acc = __builtin_amdgcn_mfma_f32_16x16x32_bf16(
                        afr[k], *(const bf16x8*)(bp + k * 32), acc, 0, 0, 0);
                int col = c * 16 + n16;
                float bb = bias_r[g][c];
                #pragma unroll
                for (int r = 0; r < 4; ++r) {
                    long row = rbase + quad * 4 + r;
                    if (row < nrows)
                        op[(size_t)row * pg + col] = (bf16)(acc[r] + bb);
                }
            }
        }
        if (!more) break;
        cvt();
        tile = next;
    }
}

// ---------------------------------------------------------------------------
// Persistent output projection: v = s*(G@W + b) + (1-s)*xres; relu; fx out.
// ---------------------------------------------------------------------------
__global__ __launch_bounds__(256) void gemm_out(
    const bf16* __restrict__ G, long gOff, int nrows,
    const bf16* __restrict__ WT, const float* __restrict__ bias,
    void* __restrict__ out, long outOff,
    const void* __restrict__ xres, long xrOff,
    const float* __restrict__ skipv, const int* fxp)
{
    int fx = *fxp;
    __shared__ bf16 sB[128 * BPITCH];
    int tid = threadIdx.x;
    #pragma unroll
    for (int it = 0; it < 8; ++it) {
        int idx = it * 256 + tid;
        int r = idx >> 4, c8 = idx & 15;
        *(bf16x8*)(&sB[r * BPITCH + c8 * 8]) = *(const bf16x8*)(WT + r * 128 + c8 * 8);
    }
    __syncthreads();

    int lane = tid & 63, wave = tid >> 6;
    int quad = lane >> 4, n16 = lane & 15;
    float sk = skipv[0];
    float s = 1.f / (1.f + __expf(-sk));
    float os = 1.f - s;
    float bias_r[8];
    #pragma unroll
    for (int c = 0; c < 8; ++c) bias_r[c] = bias[c * 16 + n16];

    int ntiles = (nrows + 63) >> 6;
    long tile = blockIdx.x;
    if (tile >= ntiles) return;

    bf16x8 afr[4], nraw[4];
    auto issue = [&](long t) {
        long ar = t * 64 + wave * 16 + n16;
        if (ar >= nrows) ar = nrows - 1;
        const bf16* ap = G + gOff + (size_t)ar * 128 + quad * 8;
        nraw[0] = *(const bf16x8*)ap;
        nraw[1] = *(const bf16x8*)(ap + 32);
        nraw[2] = *(const bf16x8*)(ap + 64);
        nraw[3] = *(const bf16x8*)(ap + 96);
    };
    issue(tile);
    afr[0] = nraw[0]; afr[1] = nraw[1]; afr[2] = nraw[2]; afr[3] = nraw[3];

    for (;;) {
        long rbase = tile * 64 + wave * 16;
        long next = tile + gridDim.x;
        bool more = (next < ntiles);
        if (more) issue(next);
        float xrv[4][8];
        #pragma unroll
        for (int r = 0; r < 4; ++r) {
            long row = rbase + quad * 4 + r;
            long rc = (row < nrows) ? row : (nrows - 1);
            #pragma unroll
            for (int c = 0; c < 8; ++c) {
                size_t xi = (size_t)xrOff + (size_t)rc * 128 + c * 16 + n16;
                xrv[r][c] = fx ? ((const float*)xres)[xi]
                               : (float)((const bf16*)xres)[xi];
            }
        }
        #pragma unroll
        for (int c = 0; c < 8; ++c) {
            f32x4 acc = {0.f, 0.f, 0.f, 0.f};
            const bf16* bp = &sB[(c * 16 + n16) * BPITCH + quad * 8];
            #pragma unroll
            for (int k = 0; k < 4; ++k)
                acc = __builtin_amdgcn_mfma_f32_16x16x32_bf16(
                    afr[k], *(const bf16x8*)(bp + k * 32), acc, 0, 0, 0);
            int col = c * 16 + n16;
            #pragma unroll
            for (int r = 0; r < 4; ++r) {
                long row = rbase + quad * 4 + r;
                if (row < nrows) {
                    float v = acc[r] + bias_r[c];
                    v = s * v + os * xrv[r][c];
                    v = fmaxf(v, 0.f);
                    size_t oi = (size_t)outOff + (size_t)row * 128 + col;
                    if (fx) ((float*)out)[oi] = v; else ((bf16*)out)[oi] = (bf16)v;
                }
            }
        }
        if (!more) break;
        afr[0] = nraw[0]; afr[1] = nraw[1]; afr[2] = nraw[2]; afr[3] = nraw[3];
        tile = next;
    }
}

// ---------------------------------------------------------------------------
// Online-softmax aggregation, 4-state ILP: 1 wave/node; lane -> 2 dims;
// head = lane>>4. 4 edges/iter with independent (m,l,a0,a1) states ->
// interleaved swizzle/exp chains; VALU-only merge at node end.
// Alpha is in log2 domain (log2e folded into K prep) -> bare v_exp_f32.
// ---------------------------------------------------------------------------
#define AGG_UPD(M, L, A0, A1, P, VU)                                    \
    {                                                                   \
        float nm = fmaxf(M, P);                                         \
        float sc = exp2f(M - nm);                                       \
        float pe = exp2f(P - nm);                                       \
        L = L * sc + pe;                                                \
        A0 = A0 * sc + pe * bflo(VU);                                   \
        A1 = A1 * sc + pe * bfhi(VU);                                   \
        M = nm;                                                         \
    }

#define AGG_MERGE(M, L, A0, A1, MS, LS, AS0, AS1)                       \
    {                                                                   \
        float nm = fmaxf(M, MS);                                        \
        float s0 = exp2f(M - nm);                                       \
        float s1 = exp2f(MS - nm);                                      \
        L = L * s0 + LS * s1;                                           \
        A0 = A0 * s0 + AS0 * s1;                                        \
        A1 = A1 * s0 + AS1 * s1;                                        \
        M = nm;                                                         \
    }

__global__ __launch_bounds__(256) void edge_agg(
    const int* __restrict__ rp, const unsigned* __restrict__ adj,
    const bf16* Q, const bf16* __restrict__ KEVE, bf16* G, int n) {
    int lane = threadIdx.x & 63;
    int node = blockIdx.x * 4 + (threadIdx.x >> 6);
    if (node >= n) return;
    unsigned qu = *(const unsigned*)(Q + (size_t)node * 128 + lane * 2);
    float q0 = bflo(qu), q1 = bfhi(qu);
    int beg = rp[node], end = rp[node + 1];

    float m0 = -3.4e38f, l0 = 0.f, x00 = 0.f, x01 = 0.f;
    float m1 = -3.4e38f, l1 = 0.f, x10 = 0.f, x11 = 0.f;
    float m2 = -3.4e38f, l2 = 0.f, x20 = 0.f, x21 = 0.f;
    float m3 = -3.4e38f, l3 = 0.f, x30 = 0.f, x31 = 0.f;

    int i = beg;
    for (; i + 4 <= end; i += 4) {
        unsigned r0 = adj[i], r1 = adj[i + 1], r2 = adj[i + 2], r3 = adj[i + 3];
        const bf16* k0 = KEVE + (size_t)r0 * 256;
        const bf16* k1 = KEVE + (size_t)r1 * 256;
        const bf16* k2 = KEVE + (size_t)r2 * 256;
        const bf16* k3 = KEVE + (size_t)r3 * 256;
        unsigned ku0 = *(const unsigned*)(k0 + lane * 2);
        unsigned ku1 = *(const unsigned*)(k1 + lane * 2);
        unsigned ku2 = *(const unsigned*)(k2 + lane * 2);
        unsigned ku3 = *(const unsigned*)(k3 + lane * 2);
        unsigned vu0 = *(const unsigned*)(k0 + 128 + lane * 2);
        unsigned vu1 = *(const unsigned*)(k1 + 128 + lane * 2);
        unsigned vu2 = *(const unsigned*)(k2 + 128 + lane * 2);
        unsigned vu3 = *(const unsigned*)(k3 + 128 + lane * 2);
        float p0 = q0 * bflo(ku0) + q1 * bfhi(ku0);
        float p1 = q0 * bflo(ku1) + q1 * bfhi(ku1);
        float p2 = q0 * bflo(ku2) + q1 * bfhi(ku2);
        float p3 = q0 * bflo(ku3) + q1 * bfhi(ku3);
        p0 += __shfl_xor(p0, 1); p1 += __shfl_xor(p1, 1);
        p2 += __shfl_xor(p2, 1); p3 += __shfl_xor(p3, 1);
        p0 += __shfl_xor(p0, 2); p1 += __shfl_xor(p1, 2);
        p2 += __shfl_xor(p2, 2); p3 += __shfl_xor(p3, 2);
        p0 += __shfl_xor(p0, 4); p1 += __shfl_xor(p1, 4);
        p2 += __shfl_xor(p2, 4); p3 += __shfl_xor(p3, 4);
        p0 += __shfl_xor(p0, 8); p1 += __shfl_xor(p1, 8);
        p2 += __shfl_xor(p2, 8); p3 += __shfl_xor(p3, 8);
        AGG_UPD(m0, l0, x00, x01, p0, vu0);
        AGG_UPD(m1, l1, x10, x11, p1, vu1);
        AGG_UPD(m2, l2, x20, x21, p2, vu2);
        AGG_UPD(m3, l3, x30, x31, p3, vu3);
    }
    for (; i < end; ++i) {
        unsigned r0 = adj[i];
        const bf16* k0 = KEVE + (size_t)r0 * 256;
        unsigned ku0 = *(const unsigned*)(k0 + lane * 2);
        unsigned vu0 = *(const unsigned*)(k0 + 128 + lane * 2);
        float p0 = q0 * bflo(ku0) + q1 * bfhi(ku0);
        p0 += __shfl_xor(p0, 1);
        p0 += __shfl_xor(p0, 2);
        p0 += __shfl_xor(p0, 4);
        p0 += __shfl_xor(p0, 8);
        AGG_UPD(m0, l0, x00, x01, p0, vu0);
    }
    // tree merge: 1->0, 3->2, 2->0 (VALU only; empty states contribute 0)
    AGG_MERGE(m0, l0, x00, x01, m1, l1, x10, x11);
    AGG_MERGE(m2, l2, x20, x21, m3, l3, x30, x31);
    AGG_MERGE(m0, l0, x00, x01, m2, l2, x20, x21);

    float inv = (end > beg) ? 1.f / l0 : 0.f;
    float g0 = gelu_exact(x00 * inv);
    float g1 = gelu_exact(x01 * inv);
    *(unsigned*)(G + (size_t)node * 128 + lane * 2) = f2bfbits(g0) | (f2bfbits(g1) << 16);
}

// ---------------------------------------------------------------------------
// Logits + sentinels (NaN->12345, inf->54321)
// ---------------------------------------------------------------------------
__global__ __launch_bounds__(256) void logits_k(
    const void* X, size_t xOff, const float* __restrict__ W,
    const float* __restrict__ B, void* out, int n, const int* fxp) {
    int fx = *fxp;
    int lane = threadIdx.x & 63;
    int node = blockIdx.x * 4 + (threadIdx.x >> 6);
    if (node >= n) return;
    size_t xb = xOff + (size_t)node * 128;
    int d0 = lane * 2;
    float x0 = ldx(X, xb + d0, fx), x1 = ldx(X, xb + d0 + 1, fx);
    float p0 = x0 * W[d0 * 3 + 0] + x1 * W[d0 * 3 + 3];
    float p1 = x0 * W[d0 * 3 + 1] + x1 * W[d0 * 3 + 4];
    float p2 = x0 * W[d0 * 3 + 2] + x1 * W[d0 * 3 + 5];
    for (int off = 1; off < 64; off <<= 1) {
        p0 += __shfl_xor(p0, off);
        p1 += __shfl_xor(p1, off);
        p2 += __shfl_xor(p2, off);
    }
    if (lane == 0) {
        p0 += B[0]; p1 += B[1]; p2 += B[2];
        if (p0 != p0) p0 = 12345.f; else if (fabsf(p0) > 1e30f) p0 = 54321.f;
        if (p1 != p1) p1 = 12345.f; else if (fabsf(p1) > 1e30f) p1 = 54321.f;
        if (p2 != p2) p2 = 12345.f; else if (fabsf(p2) > 1e30f) p2 = 54321.f;
        size_t ob = (size_t)node * 3;
        if (fx) {
            ((float*)out)[ob] = p0; ((float*)out)[ob + 1] = p1; ((float*)out)[ob + 2] = p2;
        } else {
            ((bf16*)out)[ob] = (bf16)p0; ((bf16*)out)[ob + 1] = (bf16)p1;
            ((bf16*)out)[ob + 2] = (bf16)p2;
        }
    }
}

// ---------------------------------------------------------------------------

extern "C" void kernel_launch(void* const* d_in, const int* in_sizes, int n_in,
                              void* d_out, int out_size, void* d_ws, size_t ws_size,
                              hipStream_t stream) {
    (void)n_in; (void)out_size;

    const void* x_in[3] = {d_in[0], d_in[1], d_in[2]};
    const int* ei[4] = {(const int*)d_in[3], (const int*)d_in[4],
                        (const int*)d_in[5], (const int*)d_in[6]};

    // ---- KEVE sizing: prefer disjoint regions per edge type (one proj pass) ----
    size_t KROWS = 400000;
    {
        size_t need = 0;
        auto acc = [&](size_t b) { need += (b + 255) & ~(size_t)255; };
        acc((300000ull * 128 + KROWS * 256) * 2);
        acc(2ull * 11 * 16384 * 2);
        acc(2ull * 3 * 16384 * 2);
        acc(2ull * 1408 * 4);
        acc(2ull * 384 * 4);
        acc(2ull * 3 * 4);
        acc(384ull * 4);
        acc(3ull * 4);
        acc(2ull * 4);
        acc(300000ull * 4);
        acc(300003ull * 4);
        acc(300000ull * 4);
        acc(800000ull * 4);
        acc(3ull * 256 * 4);
        if (need > ws_size) KROWS = 200000;
    }
    const int big = (KROWS == 400000);
    int lb[4];
    if (big) { lb[0] = 0; lb[1] = 150000; lb[2] = 200000; lb[3] = 300000; }
    else     { lb[0] = 0; lb[1] = 150000; lb[2] = 0;      lb[3] = 100000; }

    // ---- workspace carve ----
    char* p = (char*)d_ws;
    auto alloc = [&](size_t b) { char* r = p; p += (b + 255) & ~(size_t)255; return r; };
    bf16*  QG    = (bf16*)alloc((300000ull * 128 + KROWS * 256) * 2);  // Q/G pool + KEVE
    bf16*  KEVE  = QG + QGELEMS;
    bf16*  wpool = (bf16*)alloc(2ull * 11 * 16384 * 2);  // per L: 3 q WT, 8 kv WT
    bf16*  WaT   = (bf16*)alloc(2ull * 3 * 16384 * 2);
    float* bpool = (float*)alloc(2ull * 1408 * 4);       // per L: 384 qb, 1024 kvb
    float* abC   = (float*)alloc(2ull * 384 * 4);
    float* skipC = (float*)alloc(2ull * 3 * 4);
    float* linwC = (float*)alloc(384ull * 4);
    float* linbC = (float*)alloc(3ull * 4);
    int*   flags = (int*)alloc(2ull * 4);
    int* counts  = (int*)alloc(300000ull * 4);
    int* rowptr  = (int*)alloc(300003ull * 4);
    int* cursor  = (int*)alloc(300000ull * 4);
    unsigned* adj = (unsigned*)alloc(800000ull * 4);
    int* bsum    = (int*)alloc(3ull * 256 * 4);

    int* fxp = flags;      // x / output dtype
    int* fwp = flags + 1;  // weight dtype

    const int Ns[3]    = {N0T, N1T, N2T};
    const int baseN[3] = {0, 100000, 250000};
    const int tot[3]   = {400000, 200000, 200000};
    int* cn[3] = {counts, counts + 100000, counts + 250000};
    int* rp[3] = {rowptr, rowptr + 100001, rowptr + 250002};
    int* cu[3] = {cursor, cursor + 100000, cursor + 250000};
    unsigned* aj[3] = {adj, adj + 400000, adj + 600000};
    const long dxsOff[3] = {300000, 13100000, 32300000};

    // ---- dtype detection ----
    detect_k<<<1, 256, 0, stream>>>(d_in[0], fxp);
    detect_k<<<1, 256, 0, stream>>>(d_in[7], fwp);

    // ---- weight prep (dict vs signature order adaptive) ----
    for (int L = 0; L < 2; ++L) {
        int b = 7 + 12 * L;
        bool sig = (in_sizes[b + 1] == 384);  // sig: kw,kb,qw,qb,vw,vb,aw,ab
        int ikw, iqw, ivw, iaw, ikb, iqb, ivb, iab;
        if (sig) { ikw = b; ikb = b + 1; iqw = b + 2; iqb = b + 3;
                   ivw = b + 4; ivb = b + 5; iaw = b + 6; iab = b + 7; }
        else     { ikw = b; iqw = b + 1; ivw = b + 2; iaw = b + 3;
                   ikb = b + 4; iqb = b + 5; ivb = b + 6; iab = b + 7; }
        transpose128f<<<192, 256, 0, stream>>>(d_in[iqw], wpool + (size_t)L * 11 * 16384, fwp);
        transpose128f<<<192, 256, 0, stream>>>(d_in[iaw], WaT + (size_t)L * 49152, fwp);
        prep_kv<<<512, 256, 0, stream>>>(d_in[ikw], d_in[ivw], d_in[b + 8], d_in[b + 9],
                                         d_in[b + 10], wpool + ((size_t)L * 11 + 3) * 16384, fwp);
        prep_kvbias<<<4, 256, 0, stream>>>(d_in[ikb], d_in[ivb], d_in[b + 8], d_in[b + 9],
                                           d_in[b + 10], bpool + L * 1408 + 384, fwp);
        conv_f32_k<<<2, 256, 0, stream>>>(d_in[iqb], bpool + L * 1408, 384, fwp);
        conv_f32_k<<<2, 256, 0, stream>>>(d_in[iab], abC + L * 384, 384, fwp);
        conv_f32_k<<<1, 256, 0, stream>>>(d_in[b + 11], skipC + L * 3, 3, fwp);
    }
    conv_f32_k<<<2, 256, 0, stream>>>(d_in[31], linwC, 384, fwp);
    conv_f32_k<<<1, 256, 0, stream>>>(d_in[32], linbC, 3, fwp);

    // ---- CSR build ----
    zero_i32<<<1172, 256, 0, stream>>>(counts, 300000);
    hist_k<<<3125, 256, 0, stream>>>(ei[0], ei[1], ei[2], ei[3], cn[0], cn[1], cn[2]);
    for (int t = 0; t < 3; ++t) {
        int nb = (Ns[t] + 2047) / 2048;
        scan1<<<nb, 256, 0, stream>>>(cn[t], Ns[t], rp[t], bsum + t * 256);
        scan2<<<1, 256, 0, stream>>>(bsum + t * 256, nb);
        scan3<<<(Ns[t] + 255) / 256, 256, 0, stream>>>(rp[t], bsum + t * 256, cu[t], Ns[t], tot[t]);
    }
    fill_k<<<3125, 256, 0, stream>>>(ei[0], ei[1], ei[2], ei[3],
                                     cu[0], cu[1], cu[2], aj[0], aj[1], aj[2],
                                     lb[0], lb[1], lb[2], lb[3]);

    // ---- two HGT layers ----
    for (int L = 0; L < 2; ++L) {
        const void* xp[3]; long xo[3];
        for (int t = 0; t < 3; ++t) {
            xp[t] = L ? (const void*)d_out : x_in[t];
            xo[t] = L ? dxsOff[t] : 0;
        }

        auto WQi  = [&](int t) { return (L * 11 + t) * 16384; };
        auto WKVi = [&](int e, int k) { return (L * 11 + 3 + e * 2 + k) * 16384; };
        auto BQi  = [&](int t) { return L * 1408 + t * 128; };
        auto BKVi = [&](int e, int k) { return L * 1408 + 384 + (e * 2 + k) * 128; };
        auto OQ   = [&](int t) { return baseN[t] * 128; };
        auto OKe  = [&](int e) { return QGELEMS + lb[e] * 256; };

        auto proj = [&](int st, int ng,
                        int w0, int w1, int w2, int bb0, int bb1, int bb2,
                        int oo0, int oo1, int oo2, int pp0, int pp1, int pp2) {
            int nt = (Ns[st] + 255) / 256;
            int grid = nt < 256 ? nt : 256;
            proj_fused<<<grid, 1024, 0, stream>>>(xp[st], xo[st], Ns[st],
                wpool, bpool, QG, ng, w0, w1, w2, bb0, bb1, bb2,
                oo0, oo1, oo2, pp0, pp1, pp2, fxp);
        };
        auto agg = [&](int t) {
            edge_agg<<<(Ns[t] + 3) / 4, 256, 0, stream>>>(
                rp[t], aj[t], QG + (size_t)baseN[t] * 128, KEVE,
                QG + (size_t)baseN[t] * 128, Ns[t]);
        };
        auto outp = [&](int t) {
            int nt = (Ns[t] + 63) / 64;
            int grid = nt < 512 ? nt : 512;
            gemm_out<<<grid, 256, 0, stream>>>(
                QG, (long)baseN[t] * 128, Ns[t],
                WaT + ((size_t)L * 3 + t) * 16384, abC + L * 384 + t * 128,
                d_out, dxsOff[t], xp[t], xo[t], skipC + L * 3 + t, fxp);
        };

        if (big) {
            proj(1, 3, WQi(1), WKVi(0, 0), WKVi(0, 1), BQi(1), BKVi(0, 0), BKVi(0, 1),
                 OQ(1), OKe(0), OKe(0) + 128, 128, 256, 256);
            proj(2, 3, WQi(2), WKVi(1, 0), WKVi(1, 1), BQi(2), BKVi(1, 0), BKVi(1, 1),
                 OQ(2), OKe(1), OKe(1) + 128, 128, 256, 256);
            proj(0, 3, WQi(0), WKVi(2, 0), WKVi(2, 1), BQi(0), BKVi(2, 0), BKVi(2, 1),
                 OQ(0), OKe(2), OKe(2) + 128, 128, 256, 256);
            proj(0, 2, WKVi(3, 0), WKVi(3, 1), WKVi(3, 1), BKVi(3, 0), BKVi(3, 1), BKVi(3, 1),
                 OKe(3), OKe(3) + 128, OKe(3) + 128, 256, 256, 256);
            agg(0); agg(1); agg(2);
        } else {
            proj(0, 1, WQi(0), WQi(0), WQi(0), BQi(0), BQi(0), BQi(0),
                 OQ(0), OQ(0), OQ(0), 128, 128, 128);
            proj(1, 3, WQi(1), WKVi(0, 0), WKVi(0, 1), BQi(1), BKVi(0, 0), BKVi(0, 1),
                 OQ(1), OKe(0), OKe(0) + 128, 128, 256, 256);
            proj(2, 3, WQi(2), WKVi(1, 0), WKVi(1, 1), BQi(2), BKVi(1, 0), BKVi(1, 1),
                 OQ(2), OKe(1), OKe(1) + 128, 128, 256, 256);
            agg(0);
            proj(0, 2, WKVi(2, 0), WKVi(2, 1), WKVi(2, 1), BKVi(2, 0), BKVi(2, 1), BKVi(2, 1),
                 OKe(2), OKe(2) + 128, OKe(2) + 128, 256, 256, 256);
            proj(0, 2, WKVi(3, 0), WKVi(3, 1), WKVi(3, 1), BKVi(3, 0), BKVi(3, 1), BKVi(3, 1),
                 OKe(3), OKe(3) + 128, OKe(3) + 128, 256, 256, 256);
            agg(1); agg(2);
        }
        outp(0); outp(1); outp(2);
    }

    // ---- logits head ----
    logits_k<<<25000, 256, 0, stream>>>(d_out, dxsOff[0], linwC, linbC, d_out, N0T, fxp);
}

// Round 3
// 1278.360 us; speedup vs baseline: 1.1713x; 1.1713x over previous
//
#include <hip/hip_runtime.h>
#include <hip/hip_bf16.h>
#include <math.h>

// ---------------------------------------------------------------------------
// BigHeteroGNN — ROUND 8: un-spill proj (512thr) + MFMA operand swap.
// R7 post-mortem: 1024thr forced 64 VGPRs -> prefetch+bias state spilled ->
// proj 116us. Fix: 512thr/128-row tiles. New: swap mfma args (A/B frags are
// layout-symmetric) so each lane holds 4 CONSECUTIVE out-cols of one row ->
// 8B packed stores (4x fewer store instrs), bias via LDS broadcast reads,
// gemm_out xres/out accesses vectorized. edge_agg keeps R7 4-state ILP.
// ---------------------------------------------------------------------------

typedef __bf16 bf16;
typedef __bf16 bf16x8 __attribute__((ext_vector_type(8)));
typedef float  f32x4  __attribute__((ext_vector_type(4)));

#define NE 200000
#define N0T 100000
#define N1T 150000
#define N2T 50000
#define BPITCH 136          // 272B stride -> 2-way LDS bank alias (free, m136)
#define QGELEMS 38400000    // 300000 * 128
// fold: 1/sqrt(32) * log2(e)  (alpha kept in log2 domain; softmax invariant)
#define KSCALE (0.17677669529663687f * 1.4426950408889634f)

__device__ inline float bflo(unsigned u) { return __uint_as_float(u << 16); }
__device__ inline float bfhi(unsigned u) { return __uint_as_float(u & 0xFFFF0000u); }
__device__ inline unsigned f2bfbits(float f) {
    unsigned x = __float_as_uint(f);
    return ((x + 0x7FFFu + ((x >> 16) & 1u)) >> 16) & 0xFFFFu;  // RNE
}
__device__ inline unsigned pk2(float a, float b) {
    return f2bfbits(a) | (f2bfbits(b) << 16);
}
__device__ inline float gelu_exact(float x) {
    return 0.5f * x * (1.0f + erff(x * 0.70710678118654752f));
}
__device__ inline float ldx(const void* p, size_t i, int f) {
    return f ? ((const float*)p)[i] : (float)((const bf16*)p)[i];
}

// ---------------------------------------------------------------------------
// Dtype detection (validated R4): 1 = float32, 0 = bf16.
// ---------------------------------------------------------------------------
__device__ inline int plausible(float v) {
    float a = fabsf(v);
    return (v == 0.f) || (a > 1e-8f && a < 1e8f);
}

__global__ void detect_k(const void* p, int* flag) {
    __shared__ int cF, cB;
    int tid = threadIdx.x;
    if (tid == 0) { cF = 0; cB = 0; }
    __syncthreads();
    float vf = ((const float*)p)[tid];
    float b0 = (float)((const bf16*)p)[2 * tid];
    float b1 = (float)((const bf16*)p)[2 * tid + 1];
    if (plausible(vf)) atomicAdd(&cF, 1);
    if (plausible(b0) && plausible(b1)) atomicAdd(&cB, 1);
    __syncthreads();
    if (tid == 0) *flag = (cF > cB) ? 1 : 0;
}

__global__ void conv_f32_k(const void* src, float* dst, int n, const int* flagp) {
    int f = *flagp;
    int i = blockIdx.x * 256 + threadIdx.x;
    if (i >= n) return;
    dst[i] = ldx(src, i, f);
}

// ---------------------------------------------------------------------------
// Weight prep (canonical bf16, TRANSPOSED for B-staging: WT[col][k])
// ---------------------------------------------------------------------------
__global__ void transpose128f(const void* W, bf16* __restrict__ WT, const int* fwp) {
    int fw = *fwp;
    int gid = blockIdx.x * 256 + threadIdx.x;
    if (gid >= 3 * 16384) return;
    int t = gid >> 14, r = (gid >> 7) & 127, c = gid & 127;
    WT[gid] = (bf16)ldx(W, (size_t)(t << 14) + c * 128 + r, fw);
}

// WkvT[e][kind][j][i] = (w @ blockdiag(rel))[i][j]; kind0=k(arel*prel*log2e/sqrt d),1=v(mrel)
__global__ void prep_kv(const void* kw, const void* vw, const void* arel,
                        const void* mrel, const void* prel,
                        bf16* __restrict__ WkvT, const int* fwp) {
    int fw = *fwp;
    int gid = blockIdx.x * 256 + threadIdx.x;
    if (gid >= 4 * 2 * 128 * 128) return;
    int i = gid & 127;
    int j = (gid >> 7) & 127;
    int kind = (gid >> 14) & 1;
    int e = gid >> 15;
    const int stab[4] = {1, 2, 0, 0};
    int st = stab[e];
    int h = j >> 5, jj = j & 31;
    size_t wbase = (size_t)st * 16384;
    size_t rbase = (size_t)(e * 4 + h) * 1024;
    const void* w   = kind ? vw : kw;
    const void* rel = kind ? mrel : arel;
    float acc = 0.f;
    for (int d = 0; d < 32; ++d)
        acc += ldx(w, wbase + (size_t)i * 128 + h * 32 + d, fw) *
               ldx(rel, rbase + (size_t)d * 32 + jj, fw);
    if (!kind)
        acc *= ldx(prel, e * 4 + h, fw) * KSCALE;
    WkvT[((size_t)(e * 2 + kind) * 128 + j) * 128 + i] = (bf16)acc;
}

__global__ void prep_kvbias(const void* kb, const void* vb, const void* arel,
                            const void* mrel, const void* prel,
                            float* __restrict__ Bf, const int* fwp) {
    int fw = *fwp;
    int gid = blockIdx.x * 256 + threadIdx.x;
    if (gid >= 4 * 2 * 128) return;
    int j = gid & 127;
    int kind = (gid >> 7) & 1;
    int e = gid >> 8;
    const int stab[4] = {1, 2, 0, 0};
    int st = stab[e];
    int h = j >> 5, jj = j & 31;
    const void* b   = kind ? vb : kb;
    const void* rel = kind ? mrel : arel;
    float acc = 0.f;
    for (int d = 0; d < 32; ++d)
        acc += ldx(b, (size_t)st * 128 + h * 32 + d, fw) *
               ldx(rel, (size_t)(e * 4 + h) * 1024 + (size_t)d * 32 + jj, fw);
    if (!kind)
        acc *= ldx(prel, e * 4 + h, fw) * KSCALE;
    Bf[gid] = acc;
}

// ---------------------------------------------------------------------------
// CSR build (per dst type). Adjacency stores KEVE-buffer row ids (lb[e]+src).
// ---------------------------------------------------------------------------
__global__ void zero_i32(int* p, int n) {
    int i = blockIdx.x * 256 + threadIdx.x;
    if (i < n) p[i] = 0;
}

__global__ void hist_k(const int* __restrict__ e0, const int* __restrict__ e1,
                       const int* __restrict__ e2, const int* __restrict__ e3,
                       int* c0, int* c1, int* c2) {
    int gid = blockIdx.x * 256 + threadIdx.x;
    if (gid >= 4 * NE) return;
    int e = gid / NE, i = gid - e * NE;
    const int* ep = (e == 0) ? e0 : (e == 1) ? e1 : (e == 2) ? e2 : e3;
    int dst = ep[NE + i];
    int* c = (e < 2) ? c0 : (e == 2) ? c1 : c2;
    atomicAdd(&c[dst], 1);
}

__global__ __launch_bounds__(256) void scan1(const int* __restrict__ cnt, int n,
                                             int* __restrict__ excl, int* __restrict__ bsums) {
    __shared__ int s[256];
    int tid = threadIdx.x;
    int base = blockIdx.x * 2048 + tid * 8;
    int v[8]; int tsum = 0;
    for (int j = 0; j < 8; ++j) {
        int idx = base + j;
        int c = (idx < n) ? cnt[idx] : 0;
        v[j] = c; tsum += c;
    }
    s[tid] = tsum; __syncthreads();
    for (int off = 1; off < 256; off <<= 1) {
        int t = 0; if (tid >= off) t = s[tid - off];
        __syncthreads(); s[tid] += t; __syncthreads();
    }
    int run = s[tid] - tsum;
    for (int j = 0; j < 8; ++j) {
        int idx = base + j;
        if (idx < n) excl[idx] = run;
        run += v[j];
    }
    if (tid == 255) bsums[blockIdx.x] = s[255];
}

__global__ void scan2(int* __restrict__ bs, int nb) {
    __shared__ int s[256];
    int tid = threadIdx.x;
    int v = (tid < nb) ? bs[tid] : 0;
    s[tid] = v; __syncthreads();
    for (int off = 1; off < 256; off <<= 1) {
        int t = 0; if (tid >= off) t = s[tid - off];
        __syncthreads(); s[tid] += t; __syncthreads();
    }
    if (tid < nb) bs[tid] = s[tid] - v;
}

__global__ void scan3(int* __restrict__ excl, const int* __restrict__ bs,
                      int* __restrict__ cursor, int n, int total) {
    int idx = blockIdx.x * 256 + threadIdx.x;
    if (idx < n) {
        int v = excl[idx] + bs[idx >> 11];
        excl[idx] = v;
        cursor[idx] = v;
    }
    if (idx == 0) excl[n] = total;
}

__global__ void fill_k(const int* __restrict__ e0, const int* __restrict__ e1,
                       const int* __restrict__ e2, const int* __restrict__ e3,
                       int* c0, int* c1, int* c2,
                       unsigned* a0, unsigned* a1, unsigned* a2,
                       int lb0, int lb1, int lb2, int lb3) {
    int gid = blockIdx.x * 256 + threadIdx.x;
    if (gid >= 4 * NE) return;
    int e = gid / NE, i = gid - e * NE;
    const int* ep = (e == 0) ? e0 : (e == 1) ? e1 : (e == 2) ? e2 : e3;
    int src = ep[i], dst = ep[NE + i];
    int lb = (e == 0) ? lb0 : (e == 1) ? lb1 : (e == 2) ? lb2 : lb3;
    int* c; unsigned* a;
    if (e < 2)      { c = c0; a = a0; }
    else if (e == 2){ c = c1; a = a1; }
    else            { c = c2; a = a2; }
    int pos = atomicAdd(&c[dst], 1);
    a[pos] = (unsigned)(lb + src);
}

// ---------------------------------------------------------------------------
// Persistent fused projection: up to 3 column-groups (Q/K/V) resident in LDS
// (staged ONCE), 512 threads (8 waves), grid-stride over 128-row tiles, A
// software-prefetched one tile ahead, no barriers in the loop.
// MFMA operand-swapped: mfma(Wfrag, xfrag) -> lane holds out cols
// c*16+quad*4+{0..3} for row n16 -> packed 8B stores, uniform predication.
// ---------------------------------------------------------------------------
__global__ __launch_bounds__(512) void proj_fused(
    const void* __restrict__ A, long aOff, int nrows,
    const bf16* __restrict__ Wb, const float* __restrict__ Bb,
    bf16* __restrict__ Ob, int ng,
    int w0, int w1, int w2, int b0, int b1, int b2,
    int o0, int o1, int o2, int p0, int p1, int p2,
    const int* fxp)
{
    int fx = *fxp;
    __shared__ bf16 sB[3 * 128 * BPITCH];   // 104448 B
    __shared__ float sBias[3 * 128];
    int tid = threadIdx.x;
    #pragma unroll
    for (int g = 0; g < 3; ++g) {
        if (g >= ng) break;
        const bf16* wt = Wb + ((g == 0) ? w0 : (g == 1) ? w1 : w2);
        for (int it = 0; it < 4; ++it) {
            int idx = it * 512 + tid;
            int r = idx >> 4, c8 = idx & 15;
            *(bf16x8*)(&sB[(g * 128 + r) * BPITCH + c8 * 8]) =
                *(const bf16x8*)(wt + r * 128 + c8 * 8);
        }
    }
    if (tid < 384) {
        int g = tid >> 7, col = tid & 127;
        int bg = (g == 0) ? b0 : (g == 1) ? b1 : b2;
        sBias[tid] = Bb[bg + col];
    }
    __syncthreads();

    int lane = tid & 63, wave = tid >> 6;
    int quad = lane >> 4, n16 = lane & 15;

    int ntiles = (nrows + 127) >> 7;
    long tile = blockIdx.x;
    if (tile >= ntiles) return;

    float4 rf[8];     // raw f32 prefetch (fx path)
    bf16x8 rb[4];     // raw bf16 prefetch
    bf16x8 afr[4];    // current A fragments

    auto issue = [&](long t) {
        long ar = t * 128 + wave * 16 + n16;
        if (ar >= nrows) ar = nrows - 1;
        size_t base = (size_t)aOff + (size_t)ar * 128 + quad * 8;
        if (fx) {
            const float* ap = (const float*)A + base;
            #pragma unroll
            for (int k = 0; k < 4; ++k) {
                rf[2 * k]     = *(const float4*)(ap + k * 32);
                rf[2 * k + 1] = *(const float4*)(ap + k * 32 + 4);
            }
        } else {
            const bf16* ap = (const bf16*)A + base;
            #pragma unroll
            for (int k = 0; k < 4; ++k) rb[k] = *(const bf16x8*)(ap + k * 32);
        }
    };
    auto cvt = [&]() {
        if (fx) {
            #pragma unroll
            for (int k = 0; k < 4; ++k) {
                float4 u = rf[2 * k], v = rf[2 * k + 1];
                bf16x8 t;
                t[0] = (bf16)u.x; t[1] = (bf16)u.y; t[2] = (bf16)u.z; t[3] = (bf16)u.w;
                t[4] = (bf16)v.x; t[5] = (bf16)v.y; t[6] = (bf16)v.z; t[7] = (bf16)v.w;
                afr[k] = t;
            }
        } else {
            #pragma unroll
            for (int k = 0; k < 4; ++k) afr[k] = rb[k];
        }
    };

    issue(tile);
    cvt();
    for (;;) {
        long next = tile + gridDim.x;
        bool more = (next < ntiles);
        if (more) issue(next);          // prefetch: hides HBM latency under MFMAs
        long row = tile * 128 + wave * 16 + n16;   // this lane's output row
        bool wr = (row < nrows);
        #pragma unroll
        for (int g = 0; g < 3; ++g) {
            if (g >= ng) break;
            bf16* op = Ob + ((g == 0) ? o0 : (g == 1) ? o1 : o2);
            int pg = (g == 0) ? p0 : (g == 1) ? p1 : p2;
            #pragma unroll
            for (int c = 0; c < 8; ++c) {
                f32x4 acc = {0.f, 0.f, 0.f, 0.f};
                const bf16* bp = &sB[(g * 128 + c * 16 + n16) * BPITCH + quad * 8];
                #pragma unroll
                for (int k = 0; k < 4; ++k)
                    acc = __builtin_amdgcn_mfma_f32_16x16x32_bf16(
                        *(const bf16x8*)(bp + k * 32), afr[k], acc, 0, 0, 0);
                // swapped: lane holds out cols c*16+quad*4+{0..3} of row n16
                if (wr) {
                    int colb = c * 16 + quad * 4;
                    float4 b4 = *(const float4*)(&sBias[g * 128 + colb]);
                    uint2 u;
                    u.x = pk2(acc[0] + b4.x, acc[1] + b4.y);
                    u.y = pk2(acc[2] + b4.z, acc[3] + b4.w);
                    *(uint2*)(op + (size_t)row * pg + colb) = u;
                }
            }
        }
        if (!more) break;
        cvt();
        tile = next;
    }
}

// ---------------------------------------------------------------------------
// Persistent output projection: v = s*(G@W + b) + (1-s)*xres; relu; fx out.
// Operand-swapped MFMA -> vectorized xres loads + wide stores.
// In-place safe for L=1 (each element read+written by the same thread).
// ---------------------------------------------------------------------------
__global__ __launch_bounds__(256) void gemm_out(
    const bf16* __restrict__ G, long gOff, int nrows,
    const bf16* __restrict__ WT, const float* __restrict__ bias,
    void* __restrict__ out, long outOff,
    const void* __restrict__ xres, long xrOff,
    const float* __restrict__ skipv, const int* fxp)
{
    int fx = *fxp;
    __shared__ bf16 sB[128 * BPITCH];
    __shared__ float sBias[128];
    int tid = threadIdx.x;
    #pragma unroll
    for (int it = 0; it < 8; ++it) {
        int idx = it * 256 + tid;
        int r = idx >> 4, c8 = idx & 15;
        *(bf16x8*)(&sB[r * BPITCH + c8 * 8]) = *(const bf16x8*)(WT + r * 128 + c8 * 8);
    }
    if (tid < 128) sBias[tid] = bias[tid];
    __syncthreads();

    int lane = tid & 63, wave = tid >> 6;
    int quad = lane >> 4, n16 = lane & 15;
    float sk = skipv[0];
    float s = 1.f / (1.f + __expf(-sk));
    float os = 1.f - s;

    int ntiles = (nrows + 63) >> 6;
    long tile = blockIdx.x;
    if (tile >= ntiles) return;

    bf16x8 afr[4], nraw[4];
    auto issue = [&](long t) {
        long ar = t * 64 + wave * 16 + n16;
        if (ar >= nrows) ar = nrows - 1;
        const bf16* ap = G + gOff + (size_t)ar * 128 + quad * 8;
        nraw[0] = *(const bf16x8*)ap;
        nraw[1] = *(const bf16x8*)(ap + 32);
        nraw[2] = *(const bf16x8*)(ap + 64);
        nraw[3] = *(const bf16x8*)(ap + 96);
    };
    issue(tile);
    afr[0] = nraw[0]; afr[1] = nraw[1]; afr[2] = nraw[2]; afr[3] = nraw[3];

    for (;;) {
        long row = tile * 64 + wave * 16 + n16;
        bool wr = (row < nrows);
        long rc = wr ? row : (nrows - 1);
        long next = tile + gridDim.x;
        bool more = (next < ntiles);
        if (more) issue(next);
        // xres for this lane's row (issued before MFMAs; used in epilogue)
        float xrv[8][4];
        #pragma unroll
        for (int c = 0; c < 8; ++c) {
            size_t xi = (size_t)xrOff + (size_t)rc * 128 + c * 16 + quad * 4;
            if (fx) {
                float4 u = *(const float4*)((const float*)xres + xi);
                xrv[c][0] = u.x; xrv[c][1] = u.y; xrv[c][2] = u.z; xrv[c][3] = u.w;
            } else {
                uint2 u = *(const uint2*)((const bf16*)xres + xi);
                xrv[c][0] = bflo(u.x); xrv[c][1] = bfhi(u.x);
                xrv[c][2] = bflo(u.y); xrv[c][3] = bfhi(u.y);
            }
        }
        #pragma unroll
        for (int c = 0; c < 8; ++c) {
            f32x4 acc = {0.f, 0.f, 0.f, 0.f};
            const bf16* bp = &sB[(c * 16 + n16) * BPITCH + quad * 8];
            #pragma unroll
            for (int k = 0; k < 4; ++k)
                acc = __builtin_amdgcn_mfma_f32_16x16x32_bf16(
                    *(const bf16x8*)(bp + k * 32), afr[k], acc, 0, 0, 0);
            if (wr) {
                int colb = c * 16 + quad * 4;
                float4 b4 = *(const float4*)(&sBias[colb]);
                float v0 = fmaxf(s * (acc[0] + b4.x) + os * xrv[c][0], 0.f);
                float v1 = fmaxf(s * (acc[1] + b4.y) + os * xrv[c][1], 0.f);
                float v2 = fmaxf(s * (acc[2] + b4.z) + os * xrv[c][2], 0.f);
                float v3 = fmaxf(s * (acc[3] + b4.w) + os * xrv[c][3], 0.f);
                size_t oi = (size_t)outOff + (size_t)row * 128 + colb;
                if (fx) {
                    float4 u = {v0, v1, v2, v3};
                    *(float4*)((float*)out + oi) = u;
                } else {
                    uint2 u; u.x = pk2(v0, v1); u.y = pk2(v2, v3);
                    *(uint2*)((bf16*)out + oi) = u;
                }
            }
        }
        if (!more) break;
        afr[0] = nraw[0]; afr[1] = nraw[1]; afr[2] = nraw[2]; afr[3] = nraw[3];
        tile = next;
    }
}

// ---------------------------------------------------------------------------
// Online-softmax aggregation, 4-state ILP: 1 wave/node; lane -> 2 dims;
// head = lane>>4. 4 edges/iter with independent (m,l,a0,a1) states ->
// interleaved swizzle/exp chains; VALU-only merge at node end.
// Alpha is in log2 domain (log2e folded into K prep) -> bare v_exp_f32.
// ---------------------------------------------------------------------------
#define AGG_UPD(M, L, A0, A1, P, VU)                                    \
    {                                                                   \
        float nm = fmaxf(M, P);                                         \
        float sc = exp2f(M - nm);                                       \
        float pe = exp2f(P - nm);                                       \
        L = L * sc + pe;                                                \
        A0 = A0 * sc + pe * bflo(VU);                                   \
        A1 = A1 * sc + pe * bfhi(VU);                                   \
        M = nm;                                                         \
    }

#define AGG_MERGE(M, L, A0, A1, MS, LS, AS0, AS1)                       \
    {                                                                   \
        float nm = fmaxf(M, MS);                                        \
        float s0 = exp2f(M - nm);                                       \
        float s1 = exp2f(MS - nm);                                      \
        L = L * s0 + LS * s1;                                           \
        A0 = A0 * s0 + AS0 * s1;                                        \
        A1 = A1 * s0 + AS1 * s1;                                        \
        M = nm;                                                         \
    }

__global__ __launch_bounds__(256) void edge_agg(
    const int* __restrict__ rp, const unsigned* __restrict__ adj,
    const bf16* Q, const bf16* __restrict__ KEVE, bf16* G, int n) {
    int lane = threadIdx.x & 63;
    int node = blockIdx.x * 4 + (threadIdx.x >> 6);
    if (node >= n) return;
    unsigned qu = *(const unsigned*)(Q + (size_t)node * 128 + lane * 2);
    float q0 = bflo(qu), q1 = bfhi(qu);
    int beg = rp[node], end = rp[node + 1];

    float m0 = -3.4e38f, l0 = 0.f, x00 = 0.f, x01 = 0.f;
    float m1 = -3.4e38f, l1 = 0.f, x10 = 0.f, x11 = 0.f;
    float m2 = -3.4e38f, l2 = 0.f, x20 = 0.f, x21 = 0.f;
    float m3 = -3.4e38f, l3 = 0.f, x30 = 0.f, x31 = 0.f;

    int i = beg;
    for (; i + 4 <= end; i += 4) {
        unsigned r0 = adj[i], r1 = adj[i + 1], r2 = adj[i + 2], r3 = adj[i + 3];
        const bf16* k0 = KEVE + (size_t)r0 * 256;
        const bf16* k1 = KEVE + (size_t)r1 * 256;
        const bf16* k2 = KEVE + (size_t)r2 * 256;
        const bf16* k3 = KEVE + (size_t)r3 * 256;
        unsigned ku0 = *(const unsigned*)(k0 + lane * 2);
        unsigned ku1 = *(const unsigned*)(k1 + lane * 2);
        unsigned ku2 = *(const unsigned*)(k2 + lane * 2);
        unsigned ku3 = *(const unsigned*)(k3 + lane * 2);
        unsigned vu0 = *(const unsigned*)(k0 + 128 + lane * 2);
        unsigned vu1 = *(const unsigned*)(k1 + 128 + lane * 2);
        unsigned vu2 = *(const unsigned*)(k2 + 128 + lane * 2);
        unsigned vu3 = *(const unsigned*)(k3 + 128 + lane * 2);
        float p0 = q0 * bflo(ku0) + q1 * bfhi(ku0);
        float p1 = q0 * bflo(ku1) + q1 * bfhi(ku1);
        float p2 = q0 * bflo(ku2) + q1 * bfhi(ku2);
        float p3 = q0 * bflo(ku3) + q1 * bfhi(ku3);
        p0 += __shfl_xor(p0, 1); p1 += __shfl_xor(p1, 1);
        p2 += __shfl_xor(p2, 1); p3 += __shfl_xor(p3, 1);
        p0 += __shfl_xor(p0, 2); p1 += __shfl_xor(p1, 2);
        p2 += __shfl_xor(p2, 2); p3 += __shfl_xor(p3, 2);
        p0 += __shfl_xor(p0, 4); p1 += __shfl_xor(p1, 4);
        p2 += __shfl_xor(p2, 4); p3 += __shfl_xor(p3, 4);
        p0 += __shfl_xor(p0, 8); p1 += __shfl_xor(p1, 8);
        p2 += __shfl_xor(p2, 8); p3 += __shfl_xor(p3, 8);
        AGG_UPD(m0, l0, x00, x01, p0, vu0);
        AGG_UPD(m1, l1, x10, x11, p1, vu1);
        AGG_UPD(m2, l2, x20, x21, p2, vu2);
        AGG_UPD(m3, l3, x30, x31, p3, vu3);
    }
    for (; i < end; ++i) {
        unsigned r0 = adj[i];
        const bf16* k0 = KEVE + (size_t)r0 * 256;
        unsigned ku0 = *(const unsigned*)(k0 + lane * 2);
        unsigned vu0 = *(const unsigned*)(k0 + 128 + lane * 2);
        float p0 = q0 * bflo(ku0) + q1 * bfhi(ku0);
        p0 += __shfl_xor(p0, 1);
        p0 += __shfl_xor(p0, 2);
        p0 += __shfl_xor(p0, 4);
        p0 += __shfl_xor(p0, 8);
        AGG_UPD(m0, l0, x00, x01, p0, vu0);
    }
    // tree merge: 1->0, 3->2, 2->0 (VALU only; empty states contribute 0)
    AGG_MERGE(m0, l0, x00, x01, m1, l1, x10, x11);
    AGG_MERGE(m2, l2, x20, x21, m3, l3, x30, x31);
    AGG_MERGE(m0, l0, x00, x01, m2, l2, x20, x21);

    float inv = (end > beg) ? 1.f / l0 : 0.f;
    float g0 = gelu_exact(x00 * inv);
    float g1 = gelu_exact(x01 * inv);
    *(unsigned*)(G + (size_t)node * 128 + lane * 2) = f2bfbits(g0) | (f2bfbits(g1) << 16);
}

// ---------------------------------------------------------------------------
// Logits + sentinels (NaN->12345, inf->54321)
// ---------------------------------------------------------------------------
__global__ __launch_bounds__(256) void logits_k(
    const void* X, size_t xOff, const float* __restrict__ W,
    const float* __restrict__ B, void* out, int n, const int* fxp) {
    int fx = *fxp;
    int lane = threadIdx.x & 63;
    int node = blockIdx.x * 4 + (threadIdx.x >> 6);
    if (node >= n) return;
    size_t xb = xOff + (size_t)node * 128;
    int d0 = lane * 2;
    float x0 = ldx(X, xb + d0, fx), x1 = ldx(X, xb + d0 + 1, fx);
    float p0 = x0 * W[d0 * 3 + 0] + x1 * W[d0 * 3 + 3];
    float p1 = x0 * W[d0 * 3 + 1] + x1 * W[d0 * 3 + 4];
    float p2 = x0 * W[d0 * 3 + 2] + x1 * W[d0 * 3 + 5];
    for (int off = 1; off < 64; off <<= 1) {
        p0 += __shfl_xor(p0, off);
        p1 += __shfl_xor(p1, off);
        p2 += __shfl_xor(p2, off);
    }
    if (lane == 0) {
        p0 += B[0]; p1 += B[1]; p2 += B[2];
        if (p0 != p0) p0 = 12345.f; else if (fabsf(p0) > 1e30f) p0 = 54321.f;
        if (p1 != p1) p1 = 12345.f; else if (fabsf(p1) > 1e30f) p1 = 54321.f;
        if (p2 != p2) p2 = 12345.f; else if (fabsf(p2) > 1e30f) p2 = 54321.f;
        size_t ob = (size_t)node * 3;
        if (fx) {
            ((float*)out)[ob] = p0; ((float*)out)[ob + 1] = p1; ((float*)out)[ob + 2] = p2;
        } else {
            ((bf16*)out)[ob] = (bf16)p0; ((bf16*)out)[ob + 1] = (bf16)p1;
            ((bf16*)out)[ob + 2] = (bf16)p2;
        }
    }
}

// ---------------------------------------------------------------------------

extern "C" void kernel_launch(void* const* d_in, const int* in_sizes, int n_in,
                              void* d_out, int out_size, void* d_ws, size_t ws_size,
                              hipStream_t stream) {
    (void)n_in; (void)out_size;

    const void* x_in[3] = {d_in[0], d_in[1], d_in[2]};
    const int* ei[4] = {(const int*)d_in[3], (const int*)d_in[4],
                        (const int*)d_in[5], (const int*)d_in[6]};

    // ---- KEVE sizing: prefer disjoint regions per edge type (one proj pass) ----
    size_t KROWS = 400000;
    {
        size_t need = 0;
        auto acc = [&](size_t b) { need += (b + 255) & ~(size_t)255; };
        acc((300000ull * 128 + KROWS * 256) * 2);
        acc(2ull * 11 * 16384 * 2);
        acc(2ull * 3 * 16384 * 2);
        acc(2ull * 1408 * 4);
        acc(2ull * 384 * 4);
        acc(2ull * 3 * 4);
        acc(384ull * 4);
        acc(3ull * 4);
        acc(2ull * 4);
        acc(300000ull * 4);
        acc(300003ull * 4);
        acc(300000ull * 4);
        acc(800000ull * 4);
        acc(3ull * 256 * 4);
        if (need > ws_size) KROWS = 200000;
    }
    const int big = (KROWS == 400000);
    int lb[4];
    if (big) { lb[0] = 0; lb[1] = 150000; lb[2] = 200000; lb[3] = 300000; }
    else     { lb[0] = 0; lb[1] = 150000; lb[2] = 0;      lb[3] = 100000; }

    // ---- workspace carve ----
    char* p = (char*)d_ws;
    auto alloc = [&](size_t b) { char* r = p; p += (b + 255) & ~(size_t)255; return r; };
    bf16*  QG    = (bf16*)alloc((300000ull * 128 + KROWS * 256) * 2);  // Q/G pool + KEVE
    bf16*  KEVE  = QG + QGELEMS;
    bf16*  wpool = (bf16*)alloc(2ull * 11 * 16384 * 2);  // per L: 3 q WT, 8 kv WT
    bf16*  WaT   = (bf16*)alloc(2ull * 3 * 16384 * 2);
    float* bpool = (float*)alloc(2ull * 1408 * 4);       // per L: 384 qb, 1024 kvb
    float* abC   = (float*)alloc(2ull * 384 * 4);
    float* skipC = (float*)alloc(2ull * 3 * 4);
    float* linwC = (float*)alloc(384ull * 4);
    float* linbC = (float*)alloc(3ull * 4);
    int*   flags = (int*)alloc(2ull * 4);
    int* counts  = (int*)alloc(300000ull * 4);
    int* rowptr  = (int*)alloc(300003ull * 4);
    int* cursor  = (int*)alloc(300000ull * 4);
    unsigned* adj = (unsigned*)alloc(800000ull * 4);
    int* bsum    = (int*)alloc(3ull * 256 * 4);

    int* fxp = flags;      // x / output dtype
    int* fwp = flags + 1;  // weight dtype

    const int Ns[3]    = {N0T, N1T, N2T};
    const int baseN[3] = {0, 100000, 250000};
    const int tot[3]   = {400000, 200000, 200000};
    int* cn[3] = {counts, counts + 100000, counts + 250000};
    int* rp[3] = {rowptr, rowptr + 100001, rowptr + 250002};
    int* cu[3] = {cursor, cursor + 100000, cursor + 250000};
    unsigned* aj[3] = {adj, adj + 400000, adj + 600000};
    const long dxsOff[3] = {300000, 13100000, 32300000};

    // ---- dtype detection ----
    detect_k<<<1, 256, 0, stream>>>(d_in[0], fxp);
    detect_k<<<1, 256, 0, stream>>>(d_in[7], fwp);

    // ---- weight prep (dict vs signature order adaptive) ----
    for (int L = 0; L < 2; ++L) {
        int b = 7 + 12 * L;
        bool sig = (in_sizes[b + 1] == 384);  // sig: kw,kb,qw,qb,vw,vb,aw,ab
        int ikw, iqw, ivw, iaw, ikb, iqb, ivb, iab;
        if (sig) { ikw = b; ikb = b + 1; iqw = b + 2; iqb = b + 3;
                   ivw = b + 4; ivb = b + 5; iaw = b + 6; iab = b + 7; }
        else     { ikw = b; iqw = b + 1; ivw = b + 2; iaw = b + 3;
                   ikb = b + 4; iqb = b + 5; ivb = b + 6; iab = b + 7; }
        transpose128f<<<192, 256, 0, stream>>>(d_in[iqw], wpool + (size_t)L * 11 * 16384, fwp);
        transpose128f<<<192, 256, 0, stream>>>(d_in[iaw], WaT + (size_t)L * 49152, fwp);
        prep_kv<<<512, 256, 0, stream>>>(d_in[ikw], d_in[ivw], d_in[b + 8], d_in[b + 9],
                                         d_in[b + 10], wpool + ((size_t)L * 11 + 3) * 16384, fwp);
        prep_kvbias<<<4, 256, 0, stream>>>(d_in[ikb], d_in[ivb], d_in[b + 8], d_in[b + 9],
                                           d_in[b + 10], bpool + L * 1408 + 384, fwp);
        conv_f32_k<<<2, 256, 0, stream>>>(d_in[iqb], bpool + L * 1408, 384, fwp);
        conv_f32_k<<<2, 256, 0, stream>>>(d_in[iab], abC + L * 384, 384, fwp);
        conv_f32_k<<<1, 256, 0, stream>>>(d_in[b + 11], skipC + L * 3, 3, fwp);
    }
    conv_f32_k<<<2, 256, 0, stream>>>(d_in[31], linwC, 384, fwp);
    conv_f32_k<<<1, 256, 0, stream>>>(d_in[32], linbC, 3, fwp);

    // ---- CSR build ----
    zero_i32<<<1172, 256, 0, stream>>>(counts, 300000);
    hist_k<<<3125, 256, 0, stream>>>(ei[0], ei[1], ei[2], ei[3], cn[0], cn[1], cn[2]);
    for (int t = 0; t < 3; ++t) {
        int nb = (Ns[t] + 2047) / 2048;
        scan1<<<nb, 256, 0, stream>>>(cn[t], Ns[t], rp[t], bsum + t * 256);
        scan2<<<1, 256, 0, stream>>>(bsum + t * 256, nb);
        scan3<<<(Ns[t] + 255) / 256, 256, 0, stream>>>(rp[t], bsum + t * 256, cu[t], Ns[t], tot[t]);
    }
    fill_k<<<3125, 256, 0, stream>>>(ei[0], ei[1], ei[2], ei[3],
                                     cu[0], cu[1], cu[2], aj[0], aj[1], aj[2],
                                     lb[0], lb[1], lb[2], lb[3]);

    // ---- two HGT layers ----
    for (int L = 0; L < 2; ++L) {
        const void* xp[3]; long xo[3];
        for (int t = 0; t < 3; ++t) {
            xp[t] = L ? (const void*)d_out : x_in[t];
            xo[t] = L ? dxsOff[t] : 0;
        }

        auto WQi  = [&](int t) { return (L * 11 + t) * 16384; };
        auto WKVi = [&](int e, int k) { return (L * 11 + 3 + e * 2 + k) * 16384; };
        auto BQi  = [&](int t) { return L * 1408 + t * 128; };
        auto BKVi = [&](int e, int k) { return L * 1408 + 384 + (e * 2 + k) * 128; };
        auto OQ   = [&](int t) { return baseN[t] * 128; };
        auto OKe  = [&](int e) { return QGELEMS + lb[e] * 256; };

        auto proj = [&](int st, int ng,
                        int w0, int w1, int w2, int bb0, int bb1, int bb2,
                        int oo0, int oo1, int oo2, int pp0, int pp1, int pp2) {
            int nt = (Ns[st] + 127) / 128;
            int grid = nt < 512 ? nt : 512;
            proj_fused<<<grid, 512, 0, stream>>>(xp[st], xo[st], Ns[st],
                wpool, bpool, QG, ng, w0, w1, w2, bb0, bb1, bb2,
                oo0, oo1, oo2, pp0, pp1, pp2, fxp);
        };
        auto agg = [&](int t) {
            edge_agg<<<(Ns[t] + 3) / 4, 256, 0, stream>>>(
                rp[t], aj[t], QG + (size_t)baseN[t] * 128, KEVE,
                QG + (size_t)baseN[t] * 128, Ns[t]);
        };
        auto outp = [&](int t) {
            int nt = (Ns[t] + 63) / 64;
            int grid = nt < 512 ? nt : 512;
            gemm_out<<<grid, 256, 0, stream>>>(
                QG, (long)baseN[t] * 128, Ns[t],
                WaT + ((size_t)L * 3 + t) * 16384, abC + L * 384 + t * 128,
                d_out, dxsOff[t], xp[t], xo[t], skipC + L * 3 + t, fxp);
        };

        if (big) {
            proj(1, 3, WQi(1), WKVi(0, 0), WKVi(0, 1), BQi(1), BKVi(0, 0), BKVi(0, 1),
                 OQ(1), OKe(0), OKe(0) + 128, 128, 256, 256);
            proj(2, 3, WQi(2), WKVi(1, 0), WKVi(1, 1), BQi(2), BKVi(1, 0), BKVi(1, 1),
                 OQ(2), OKe(1), OKe(1) + 128, 128, 256, 256);
            proj(0, 3, WQi(0), WKVi(2, 0), WKVi(2, 1), BQi(0), BKVi(2, 0), BKVi(2, 1),
                 OQ(0), OKe(2), OKe(2) + 128, 128, 256, 256);
            proj(0, 2, WKVi(3, 0), WKVi(3, 1), WKVi(3, 1), BKVi(3, 0), BKVi(3, 1), BKVi(3, 1),
                 OKe(3), OKe(3) + 128, OKe(3) + 128, 256, 256, 256);
            agg(0); agg(1); agg(2);
        } else {
            proj(0, 1, WQi(0), WQi(0), WQi(0), BQi(0), BQi(0), BQi(0),
                 OQ(0), OQ(0), OQ(0), 128, 128, 128);
            proj(1, 3, WQi(1), WKVi(0, 0), WKVi(0, 1), BQi(1), BKVi(0, 0), BKVi(0, 1),
                 OQ(1), OKe(0), OKe(0) + 128, 128, 256, 256);
            proj(2, 3, WQi(2), WKVi(1, 0), WKVi(1, 1), BQi(2), BKVi(1, 0), BKVi(1, 1),
                 OQ(2), OKe(1), OKe(1) + 128, 128, 256, 256);
            agg(0);
            proj(0, 2, WKVi(2, 0), WKVi(2, 1), WKVi(2, 1), BKVi(2, 0), BKVi(2, 1), BKVi(2, 1),
                 OKe(2), OKe(2) + 128, OKe(2) + 128, 256, 256, 256);
            proj(0, 2, WKVi(3, 0), WKVi(3, 1), WKVi(3, 1), BKVi(3, 0), BKVi(3, 1), BKVi(3, 1),
                 OKe(3), OKe(3) + 128, OKe(3) + 128, 256, 256, 256);
            agg(1); agg(2);
        }
        outp(0); outp(1); outp(2);
    }

    // ---- logits head ----
    logits_k<<<25000, 256, 0, stream>>>(d_out, dxsOff[0], linwC, linbC, d_out, N0T, fxp);
}